// Round 4
// baseline (130.995 us; speedup 1.0000x reference)
//
#include <hip/hip_runtime.h>

// LSGA fused kernel, round 10: round 8 + (256,2) + vectorized xbar/hbar.
// Round-9 post-mortem: NaN fail. Three changes at once; the opaque one
// (v_cvt_pk_bf16_f32 inline asm) is the prime suspect — garbage dst bits
// are NaN as bf16. Reverted ALL inline asm; this round carries only the
// auditable plain-C changes:
//   1. __launch_bounds__(256,2): rounds 7/8 showed VGPR_Count=64 (arch half
//      of a 128 split) + ~8MB scratch writes. Cap 256 ends the split-spill.
//   2. xbar via uint4 gathers on t0-127; hbar via paired u32 LDS reads on
//      t128-255 (was: every thread doing both, uint2 + scalar).
// Keeps round-7/8 algebra: e0 deleted, in-wave softmax, Wow2 fold, 4 barriers.
//
// MFMA 16x16x32 lane mappings (verified rounds 3/4/5):
//   A-frag:  A[m = lane&15][k = (lane>>4)*8 + j]
//   B-frag:  B[k = (lane>>4)*8 + j][n = lane&15]
//   C/D:     col = lane&15, row = (lane>>4)*4 + reg

using u16 = unsigned short;
using u32 = unsigned int;
using u64 = unsigned long long;

typedef short bf16x8 __attribute__((ext_vector_type(8)));
typedef float f32x4  __attribute__((ext_vector_type(4)));

__device__ __forceinline__ float bl(u32 u) { return __uint_as_float(u << 16); }
__device__ __forceinline__ float bh(u32 u) { return __uint_as_float(u & 0xffff0000u); }
__device__ __forceinline__ float b2f(u16 u) { return __uint_as_float(((u32)u) << 16); }
__device__ __forceinline__ u16 f2b(float f) {
    u32 u = __float_as_uint(f);
    u32 r = u + 0x7fffu + ((u >> 16) & 1u);   // RNE
    return (u16)(r >> 16);
}
__device__ __forceinline__ u64 pack4(float a, float b, float c, float d) {
    return (u64)f2b(a) | ((u64)f2b(b) << 16) | ((u64)f2b(c) << 32) | ((u64)f2b(d) << 48);
}
// A-operand frag flat index for element [m][c] of a 128-col operand
__device__ __forceinline__ int fidxA(int m, int c) {
    return (((m >> 4)*4 + (c >> 5))*64 + ((c >> 3) & 3)*16 + (m & 15))*8 + (c & 7);
}

// ---------------------------------------------------------------------------
// Kernel 1 (merged): blocks 0..129 = weight fuse/pack, 130..2177 = transpose.
__global__ void __launch_bounds__(512)
k_pt(const float* __restrict__ x,
     const float* __restrict__ Wq, const float* __restrict__ bq,
     const float* __restrict__ Wk,
     const float* __restrict__ Wv, const float* __restrict__ bv,
     const float* __restrict__ Wo, const float* __restrict__ bo,
     const float* __restrict__ W1, const float* __restrict__ W2,
     u16* __restrict__ Afrag, u16* __restrict__ Wovfrag,
     u16* __restrict__ W1frag, u16* __restrict__ W2frag,
     u16* __restrict__ Wow2frag,
     float* __restrict__ bA, float* __restrict__ bov,
     u16* __restrict__ xT)
{
    const int blk = blockIdx.x, tid = threadIdx.x;

    if (blk >= 130) {
        // ---- transpose x[b][c][n] -> xT[b][n][c] (bf16), 32x32 tiles ----
        __shared__ u16 tile[32][33];
        const int blk2 = blk - 130;
        const int b  = blk2 >> 10;
        const int ct = (blk2 >> 8) & 3;
        const int nt = blk2 & 255;
        const int tx = tid & 31, ty = tid >> 5;      // 32 x 16
        const size_t xb = (size_t)b * 128 * 8192;
        #pragma unroll
        for (int j = 0; j < 2; ++j) {
            int c = ct*32 + ty + j*16;
            tile[ty + j*16][tx] = f2b(x[xb + (size_t)c * 8192 + (size_t)(nt*32 + tx)]);
        }
        __syncthreads();
        #pragma unroll
        for (int j = 0; j < 2; ++j) {
            int n = nt*32 + ty + j*16;
            xT[xb + (size_t)n * 128 + (size_t)(ct*32 + tx)] = tile[tx][ty + j*16];
        }
        return;
    }

    const int i = tid & 127, p = tid >> 7;          // 4-way K-split
    if (blk < 128) {
        __shared__ float sWk[128], sWo[128];
        __shared__ float s_pA[4][128], s_pV[4][128];
        __shared__ float sWovRow[128];
        __shared__ float s_p2[32][17];
        if (tid < 128) sWk[tid] = Wk[tid*128 + blk];
        else if (tid < 256) sWo[tid-128] = Wo[blk*128 + (tid-128)];
        __syncthreads();
        float accA = 0.f, accV = 0.f;
        #pragma unroll 8
        for (int o = p*32; o < p*32 + 32; ++o) {
            accA += sWk[o] * Wq[o*128 + i];
            accV += sWo[o] * Wv[o*128 + i];
        }
        s_pA[p][i] = accA; s_pV[p][i] = accV;
        __syncthreads();
        if (tid < 128) {
            float v = s_pA[0][tid] + s_pA[1][tid] + s_pA[2][tid] + s_pA[3][tid];
            Afrag[fidxA(blk, tid)] = f2b(v);
        } else if (tid < 256) {
            int ii = tid - 128;
            float v = s_pV[0][ii] + s_pV[1][ii] + s_pV[2][ii] + s_pV[3][ii];
            Wovfrag[fidxA(blk, ii)] = f2b(v);
            sWovRow[ii] = v;
        }
        __syncthreads();
        {   // Wow2[blk][h] = sum_c Wov[blk][c] * W2[h][c]   (h in [0,32))
            int h = tid >> 4, sub = tid & 15;
            float a = 0.f;
            #pragma unroll
            for (int jj = 0; jj < 8; ++jj)
                a += sWovRow[sub*8 + jj] * W2[h*128 + sub*8 + jj];
            s_p2[h][sub] = a;
        }
        __syncthreads();
        if (tid < 32) {
            float v = 0.f;
            #pragma unroll
            for (int s = 0; s < 16; ++s) v += s_p2[tid][s];
            // A-frag (K=32): [(mt*64 + q*16 + lmm)*8 + j], m=blk, k=tid
            Wow2frag[(((blk >> 4)*64 + (tid >> 3)*16 + (blk & 15)))*8 + (tid & 7)] = f2b(v);
        }
    } else if (blk == 128) {
        __shared__ float s_r[2][4][128];
        float a1 = 0.f, a3 = 0.f;
        #pragma unroll 8
        for (int o = p*32; o < p*32 + 32; ++o) {
            a1 += Wk[o*128 + i] * bq[o];
            a3 += Wo[i*128 + o] * bv[o];
        }
        s_r[0][p][i] = a1; s_r[1][p][i] = a3;
        __syncthreads();
        if (tid < 128) {
            bA[tid] = s_r[0][0][tid] + s_r[0][1][tid] + s_r[0][2][tid] + s_r[0][3][tid];
        } else if (tid < 256) {
            int ii = tid - 128;
            bov[ii] = s_r[1][0][ii] + s_r[1][1][ii] + s_r[1][2][ii] + s_r[1][3][ii] + bo[ii];
        }
    } else {
        // blk == 129: fragment packs for W1 / W2
        for (int e = tid; e < 4096; e += 512) {
            int ii = e & 127, r2 = e >> 7;         // r2 in [0,32)
            {   // W1frag: B-operand of H=E*W1, elem B[k=ii][n=r2]
                int nt = r2 >> 4, lmm = r2 & 15;
                int ks = ii >> 5, q = (ii >> 3) & 3, j = ii & 7;
                W1frag[((nt*4 + ks)*64 + q*16 + lmm)*8 + j] = f2b(W1[ii*32 + r2]);
            }
            {   // W2frag: A-operand of G=W2*QK, elem A[m=r2][c=ii]
                int mt = r2 >> 4, lmm = r2 & 15;
                int ks = ii >> 5, q = (ii >> 3) & 3, j = ii & 7;
                W2frag[((mt*4 + ks)*64 + q*16 + lmm)*8 + j] = f2b(W2[r2*128 + ii]);
            }
        }
    }
}

// ---------------------------------------------------------------------------
// Kernel 2: fused main. Grid 2048 x 256; 8 n per block; ~21 KB LDS; 4 barriers.
// (256,2): VGPR cap 256 -> allocator stops the 64/64 split-spill seen at
// (256,4) (VGPR_Count=64, ~8MB scratch writes in rounds 7/8).
__global__ void __launch_bounds__(256, 2)
k_main(const u16* __restrict__ xT, const float* __restrict__ coords,
       const int* __restrict__ idx, const float* __restrict__ Bg,
       const float* __restrict__ b1g, const float* __restrict__ b2g,
       const u16* __restrict__ Afrag, const u16* __restrict__ Wovfrag,
       const u16* __restrict__ W1frag, const u16* __restrict__ W2frag,
       const u16* __restrict__ Wow2frag,
       const float* __restrict__ bAg, const float* __restrict__ bovg,
       float* __restrict__ out)
{
    __shared__ __align__(16) u16   sH[128][40];      // H bf16 rows (n,k) x m
    __shared__ __align__(16) u16   s_qkb[8][136];    // qk bf16 [n][c]
    __shared__ __align__(16) u16   s_gb[8][40];      // g bf16 [n][m]
    __shared__ __align__(16) u16   s_xbb[8][136];    // xbar+b2 bf16 [n][c]
    __shared__ __align__(16) float s_del[128][4];
    __shared__ float s_attn[8][17];
    __shared__ u16   sHbar[32][12];                  // hbar bf16 [m][n]
    __shared__ __align__(16) float s_b2[128];
    __shared__ float s_bov[128], s_b1[32];
    __shared__ __align__(16) float sBgT[64][4];
    __shared__ int s_idx[128];

    const int tid = threadIdx.x;
    const int w = tid >> 6, l = tid & 63, lm = l & 15, lq = l >> 4, lmm = lm & 7;
    const int g0 = blockIdx.x * 8;
    const int bsel = g0 >> 13;
    const int n0 = g0 & 8191;
    const size_t bbase = ((size_t)bsel) << 13;
    const float inv_sqrtC = 0.08838834764831845f;

    // ---- preamble: biases/Bg + idx/delta + QK MFMA + qk pack (no barrier) ----
    if (tid < 128) { s_bov[tid] = bovg[tid]; s_b2[tid] = b2g[tid]; }
    else if (tid < 160) { s_b1[tid-128] = b1g[tid-128]; }
    sBgT[tid >> 2][tid & 3] = Bg[(tid & 3)*64 + (tid >> 2)];

    if (tid < 128) {
        int j = idx[(size_t)g0*16 + tid];
        s_idx[tid] = j;
        float4 cj = *(const float4*)&coords[(size_t)(bbase + j)*4];
        float4 cn = *(const float4*)&coords[(size_t)(g0 + (tid >> 4))*4];
        *(float4*)s_del[tid] = make_float4(cj.x-cn.x, cj.y-cn.y, cj.z-cn.z, cj.w-cn.w);
    }
    {   // QK = A*X (cols n = lm&7 duplicated; only lm<8 stored); bias from global
        f32x4 accq[2] = {{0.f,0.f,0.f,0.f},{0.f,0.f,0.f,0.f}};
        const bf16x8* Af = (const bf16x8*)Afrag;
        bf16x8 bfr[4];
        #pragma unroll
        for (int ks = 0; ks < 4; ++ks)
            bfr[ks] = *(const bf16x8*)&xT[(((size_t)(g0 + lmm)) << 7) + ks*32 + lq*8];
        #pragma unroll
        for (int mi = 0; mi < 2; ++mi) {
            const int ct = w*2 + mi;
            #pragma unroll
            for (int ks = 0; ks < 4; ++ks) {
                bf16x8 a = Af[(ct*4 + ks)*64 + l];
                accq[mi] = __builtin_amdgcn_mfma_f32_16x16x32_bf16(a, bfr[ks], accq[mi], 0, 0, 0);
            }
        }
        if (lm < 8) {
            #pragma unroll
            for (int mi = 0; mi < 2; ++mi) {
                int c0 = (w*2 + mi)*16 + lq*4;
                float4 ba4 = *(const float4*)&bAg[c0];
                *(u64*)&s_qkb[lm][c0] = pack4(accq[mi][0] + ba4.x, accq[mi][1] + ba4.y,
                                              accq[mi][2] + ba4.z, accq[mi][3] + ba4.w);
            }
        }
    }
    __syncthreads();   // B1

    // ---- H = relu(E*W1+b1) [all waves] ; G = W2*QK [w0-1] ----
    {
        const bf16x8* W1f = (const bf16x8*)W1frag;
        bf16x8 w1f[2][4];
        #pragma unroll
        for (int nt = 0; nt < 2; ++nt)
            #pragma unroll
            for (int ks = 0; ks < 4; ++ks) w1f[nt][ks] = W1f[(nt*4 + ks)*64 + l];
        #pragma unroll
        for (int mi = 0; mi < 2; ++mi) {
            const int mt = w*2 + mi;               // mt = n, lm = k
            float4 d = *(const float4*)s_del[mt*16 + lm];
            bf16x8 ea[4];
            #pragma unroll
            for (int ksp = 0; ksp < 2; ++ksp) {
                #pragma unroll
                for (int jp = 0; jp < 4; ++jp) {
                    int f = ksp*32 + lq*8 + jp*2;
                    float4 ga = *(const float4*)sBgT[f];
                    float4 gb = *(const float4*)sBgT[f+1];
                    float p0 = d.x*ga.x + d.y*ga.y + d.z*ga.z + d.w*ga.w;
                    float p1 = d.x*gb.x + d.y*gb.y + d.z*gb.z + d.w*gb.w;
                    p0 -= floorf(p0); p1 -= floorf(p1);
                    ((u32*)&ea[ksp])[jp]   = (u32)f2b(__builtin_amdgcn_sinf(p0))
                                           | ((u32)f2b(__builtin_amdgcn_sinf(p1)) << 16);
                    ((u32*)&ea[ksp+2])[jp] = (u32)f2b(__builtin_amdgcn_cosf(p0))
                                           | ((u32)f2b(__builtin_amdgcn_cosf(p1)) << 16);
                }
            }
            f32x4 acch[2] = {{0.f,0.f,0.f,0.f},{0.f,0.f,0.f,0.f}};
            #pragma unroll
            for (int ks = 0; ks < 4; ++ks) {
                acch[0] = __builtin_amdgcn_mfma_f32_16x16x32_bf16(ea[ks], w1f[0][ks], acch[0], 0,0,0);
                acch[1] = __builtin_amdgcn_mfma_f32_16x16x32_bf16(ea[ks], w1f[1][ks], acch[1], 0,0,0);
            }
            #pragma unroll
            for (int nt = 0; nt < 2; ++nt) {
                float b1v = s_b1[nt*16 + lm];
                #pragma unroll
                for (int r = 0; r < 4; ++r)
                    sH[mt*16 + lq*4 + r][nt*16 + lm] = f2b(fmaxf(acch[nt][r] + b1v, 0.f));
            }
        }
    }
    if (w < 2) {
        // G = W2*QK (m-tile = w)
        const bf16x8* W2f = (const bf16x8*)W2frag;
        f32x4 accg = {0.f,0.f,0.f,0.f};
        #pragma unroll
        for (int ks = 0; ks < 4; ++ks) {
            bf16x8 a = W2f[(w*4 + ks)*64 + l];
            bf16x8 bv = *(const bf16x8*)&s_qkb[lmm][ks*32 + lq*8];
            accg = __builtin_amdgcn_mfma_f32_16x16x32_bf16(a, bv, accg, 0, 0, 0);
        }
        if (lm < 8) {
            int m0 = w*16 + lq*4;
            *(u64*)&s_gb[lm][m0] = pack4(accg[0], accg[1], accg[2], accg[3]);
        }
    }
    __syncthreads();   // B2

    // ---- scores: S = [Xnb | H] · [qk ; g] + in-wave softmax ----
    // Neighbor-row loads hoisted to the top of the stage: 8 global loads
    // batch ahead of the 6 LDS fragment reads (short live range).
    {
        bf16x8 xnb[2][4];
        const size_t rb0 = ((size_t)(bbase + s_idx[(w*2 + 0)*16 + lm])) << 7;
        const size_t rb1 = ((size_t)(bbase + s_idx[(w*2 + 1)*16 + lm])) << 7;
        #pragma unroll
        for (int ks = 0; ks < 4; ++ks)
            xnb[0][ks] = *(const bf16x8*)&xT[rb0 + ks*32 + lq*8];
        #pragma unroll
        for (int ks = 0; ks < 4; ++ks)
            xnb[1][ks] = *(const bf16x8*)&xT[rb1 + ks*32 + lq*8];
        bf16x8 bq4[5];
        #pragma unroll
        for (int ks = 0; ks < 4; ++ks) bq4[ks] = *(const bf16x8*)&s_qkb[lmm][ks*32 + lq*8];
        bq4[4] = *(const bf16x8*)&s_gb[lmm][lq*8];
        #pragma unroll
        for (int mi = 0; mi < 2; ++mi) {
            const int mt = w*2 + mi;               // mt = n, lm = k
            f32x4 acc = {0.f,0.f,0.f,0.f};
            #pragma unroll
            for (int ks = 0; ks < 4; ++ks)
                acc = __builtin_amdgcn_mfma_f32_16x16x32_bf16(xnb[mi][ks], bq4[ks], acc, 0, 0, 0);
            {
                bf16x8 a = *(const bf16x8*)&sH[mt*16 + lm][lq*8];
                acc = __builtin_amdgcn_mfma_f32_16x16x32_bf16(a, bq4[4], acc, 0, 0, 0);
            }
            // in-wave softmax over K=16: k = lq*4+r, reduce across lq via
            // xor 16/32; e0 term dropped (k-independent => shift-invariant).
            float s0 = acc[0]*inv_sqrtC, s1 = acc[1]*inv_sqrtC;
            float s2 = acc[2]*inv_sqrtC, s3 = acc[3]*inv_sqrtC;
            float mx = fmaxf(fmaxf(s0, s1), fmaxf(s2, s3));
            mx = fmaxf(mx, __shfl_xor(mx, 16));
            mx = fmaxf(mx, __shfl_xor(mx, 32));
            float e0 = __expf(s0 - mx), e1 = __expf(s1 - mx);
            float e2 = __expf(s2 - mx), e3 = __expf(s3 - mx);
            float sm = (e0 + e1) + (e2 + e3);
            sm += __shfl_xor(sm, 16);
            sm += __shfl_xor(sm, 32);
            if (lm == mt) {
                float inv = 1.0f / sm;
                s_attn[mt][lq*4 + 0] = e0*inv;
                s_attn[mt][lq*4 + 1] = e1*inv;
                s_attn[mt][lq*4 + 2] = e2*inv;
                s_attn[mt][lq*4 + 3] = e3*inv;
            }
        }
    }
    __syncthreads();   // B3

    // ---- xbar (+b2) -> s_xbb (bf16) [t0-127, uint4] ; hbar -> sHbar [t128-255] ----
    if (tid < 128) {
        int n = tid >> 4, cs = tid & 15, c0 = cs*8;
        float a0[16];
        #pragma unroll
        for (int k = 0; k < 16; ++k) a0[k] = s_attn[n][k];
        float4 f0 = *(const float4*)&s_b2[c0];
        float4 f1 = *(const float4*)&s_b2[c0+4];
        #pragma unroll
        for (int k = 0; k < 16; ++k) {
            uint4 v = *(const uint4*)&xT[(((size_t)(bbase + s_idx[n*16 + k])) << 7) + c0];
            f0.x += a0[k]*bl(v.x); f0.y += a0[k]*bh(v.x);
            f0.z += a0[k]*bl(v.y); f0.w += a0[k]*bh(v.y);
            f1.x += a0[k]*bl(v.z); f1.y += a0[k]*bh(v.z);
            f1.z += a0[k]*bl(v.w); f1.w += a0[k]*bh(v.w);
        }
        *(u64*)&s_xbb[n][c0]   = pack4(f0.x, f0.y, f0.z, f0.w);
        *(u64*)&s_xbb[n][c0+4] = pack4(f1.x, f1.y, f1.z, f1.w);
    } else {
        int t = tid - 128;
        int n = t >> 4, m0 = (t & 15)*2;
        float h0 = 0.f, h1 = 0.f;
        #pragma unroll
        for (int k = 0; k < 16; ++k) {
            float ak = s_attn[n][k];
            u32 hv = *(const u32*)&sH[n*16 + k][m0];
            h0 += ak * bl(hv);
            h1 += ak * bh(hv);
        }
        sHbar[m0][n]   = f2b(h0);
        sHbar[m0+1][n] = f2b(h1);
    }
    __syncthreads();   // B4

    // ---- OUT = Wov*xbar + Wow2*Hbar + bov -> global ----
    {
        const bf16x8* Wvf = (const bf16x8*)Wovfrag;
        const bf16x8* W2f = (const bf16x8*)Wow2frag;
        bf16x8 bv[4];
        #pragma unroll
        for (int ks = 0; ks < 4; ++ks) bv[ks] = *(const bf16x8*)&s_xbb[lmm][ks*32 + lq*8];
        bf16x8 bvh;
        #pragma unroll
        for (int j = 0; j < 8; ++j) bvh[j] = (short)sHbar[lq*8 + j][lmm];
        #pragma unroll
        for (int mi = 0; mi < 2; ++mi) {
            const int ct = w*2 + mi;
            f32x4 acco = {0.f,0.f,0.f,0.f};
            acco = __builtin_amdgcn_mfma_f32_16x16x32_bf16(W2f[ct*64 + l], bvh, acco, 0, 0, 0);
            #pragma unroll
            for (int ks = 0; ks < 4; ++ks) {
                bf16x8 a = Wvf[(ct*4 + ks)*64 + l];
                acco = __builtin_amdgcn_mfma_f32_16x16x32_bf16(a, bv[ks], acco, 0, 0, 0);
            }
            if (lm < 8) {
                #pragma unroll
                for (int r = 0; r < 4; ++r) {
                    int o = ct*16 + lq*4 + r;
                    out[(((size_t)(bsel*128 + o)) << 13) + n0 + lm] = acco[r] + s_bov[o];
                }
            }
        }
    }
}

// ---------------------------------------------------------------------------
extern "C" void kernel_launch(void* const* d_in, const int* in_sizes, int n_in,
                              void* d_out, int out_size, void* d_ws, size_t ws_size,
                              hipStream_t stream)
{
    const float* x      = (const float*)d_in[0];
    const float* coords = (const float*)d_in[1];
    const int*   idx    = (const int*)d_in[2];
    const float* Bg     = (const float*)d_in[3];
    const float* W1     = (const float*)d_in[4];
    const float* b1     = (const float*)d_in[5];
    const float* W2     = (const float*)d_in[6];
    const float* b2     = (const float*)d_in[7];
    const float* Wq     = (const float*)d_in[8];
    const float* bq     = (const float*)d_in[9];
    const float* Wk     = (const float*)d_in[10];
    const float* bk     = (const float*)d_in[11];
    const float* Wv     = (const float*)d_in[12];
    const float* bv     = (const float*)d_in[13];
    const float* Wo     = (const float*)d_in[14];
    const float* bo     = (const float*)d_in[15];
    float* out = (float*)d_out;
    (void)bk;

    char* ws = (char*)d_ws;
    u16*   Afrag    = (u16*)(ws);              // 32768 B
    u16*   Wovfrag  = (u16*)(ws + 32768);      // 32768 B
    u16*   W1frag   = (u16*)(ws + 65536);      // 8192 B
    u16*   W2frag   = (u16*)(ws + 73728);      // 8192 B
    u16*   Wow2frag = (u16*)(ws + 81920);      // 8192 B
    float* bA       = (float*)(ws + 90112);    // 512 B
    float* bov      = (float*)(ws + 90624);    // 512 B
    u16*   xT       = (u16*)(ws + 94208);      // 4 MiB

    k_pt<<<2178, 512, 0, stream>>>(x, Wq, bq, Wk, Wv, bv, Wo, bo, W1, W2,
                                   Afrag, Wovfrag, W1frag, W2frag, Wow2frag,
                                   bA, bov, xT);
    k_main<<<2048, 256, 0, stream>>>(xT, coords, idx, Bg, b1, b2,
                                     Afrag, Wovfrag, W1frag, W2frag, Wow2frag,
                                     bA, bov, out);
}

// Round 5
// 123.650 us; speedup vs baseline: 1.0594x; 1.0594x over previous
//
#include <hip/hip_runtime.h>

// LSGA fused kernel, round 11: 16 points per block (grid 1024).
// Round-10 post-mortem: k_main ~38us, still serialization-bound; QK/G/OUT
// MFMAs ran with DUPLICATED columns (8 points in 16 cols, lmm=lm&7) = 50%
// waste, and per-block fixed costs (preamble, 4 barriers) paid every 8 points.
// This round: NPB=16 -> all 16 MFMA columns distinct (QK/OUT per-point MFMA
// cost halves), barriers/preamble amortized 2x, blocks 2048->1024.
// Keeps: e0 deleted, in-wave softmax, Wow2 fold, 4 barriers, (256,2), scalar
// f2b only (no inline asm — round-9 NaN lesson).
//
// MFMA 16x16x32 lane mappings (verified rounds 3/4/5):
//   A-frag:  A[m = lane&15][k = (lane>>4)*8 + j]
//   B-frag:  B[k = (lane>>4)*8 + j][n = lane&15]
//   C/D:     col = lane&15, row = (lane>>4)*4 + reg

using u16 = unsigned short;
using u32 = unsigned int;
using u64 = unsigned long long;

typedef short bf16x8 __attribute__((ext_vector_type(8)));
typedef float f32x4  __attribute__((ext_vector_type(4)));

__device__ __forceinline__ float bl(u32 u) { return __uint_as_float(u << 16); }
__device__ __forceinline__ float bh(u32 u) { return __uint_as_float(u & 0xffff0000u); }
__device__ __forceinline__ float b2f(u16 u) { return __uint_as_float(((u32)u) << 16); }
__device__ __forceinline__ u16 f2b(float f) {
    u32 u = __float_as_uint(f);
    u32 r = u + 0x7fffu + ((u >> 16) & 1u);   // RNE
    return (u16)(r >> 16);
}
__device__ __forceinline__ u64 pack4(float a, float b, float c, float d) {
    return (u64)f2b(a) | ((u64)f2b(b) << 16) | ((u64)f2b(c) << 32) | ((u64)f2b(d) << 48);
}
// A-operand frag flat index for element [m][c] of a 128-col operand
__device__ __forceinline__ int fidxA(int m, int c) {
    return (((m >> 4)*4 + (c >> 5))*64 + ((c >> 3) & 3)*16 + (m & 15))*8 + (c & 7);
}

// ---------------------------------------------------------------------------
// Kernel 1 (merged): blocks 0..129 = weight fuse/pack, 130..2177 = transpose.
__global__ void __launch_bounds__(512)
k_pt(const float* __restrict__ x,
     const float* __restrict__ Wq, const float* __restrict__ bq,
     const float* __restrict__ Wk,
     const float* __restrict__ Wv, const float* __restrict__ bv,
     const float* __restrict__ Wo, const float* __restrict__ bo,
     const float* __restrict__ W1, const float* __restrict__ W2,
     u16* __restrict__ Afrag, u16* __restrict__ Wovfrag,
     u16* __restrict__ W1frag, u16* __restrict__ W2frag,
     u16* __restrict__ Wow2frag,
     float* __restrict__ bA, float* __restrict__ bov,
     u16* __restrict__ xT)
{
    const int blk = blockIdx.x, tid = threadIdx.x;

    if (blk >= 130) {
        // ---- transpose x[b][c][n] -> xT[b][n][c] (bf16), 32x32 tiles ----
        __shared__ u16 tile[32][33];
        const int blk2 = blk - 130;
        const int b  = blk2 >> 10;
        const int ct = (blk2 >> 8) & 3;
        const int nt = blk2 & 255;
        const int tx = tid & 31, ty = tid >> 5;      // 32 x 16
        const size_t xb = (size_t)b * 128 * 8192;
        #pragma unroll
        for (int j = 0; j < 2; ++j) {
            int c = ct*32 + ty + j*16;
            tile[ty + j*16][tx] = f2b(x[xb + (size_t)c * 8192 + (size_t)(nt*32 + tx)]);
        }
        __syncthreads();
        #pragma unroll
        for (int j = 0; j < 2; ++j) {
            int n = nt*32 + ty + j*16;
            xT[xb + (size_t)n * 128 + (size_t)(ct*32 + tx)] = tile[tx][ty + j*16];
        }
        return;
    }

    const int i = tid & 127, p = tid >> 7;          // 4-way K-split
    if (blk < 128) {
        __shared__ float sWk[128], sWo[128];
        __shared__ float s_pA[4][128], s_pV[4][128];
        __shared__ float sWovRow[128];
        __shared__ float s_p2[32][17];
        if (tid < 128) sWk[tid] = Wk[tid*128 + blk];
        else if (tid < 256) sWo[tid-128] = Wo[blk*128 + (tid-128)];
        __syncthreads();
        float accA = 0.f, accV = 0.f;
        #pragma unroll 8
        for (int o = p*32; o < p*32 + 32; ++o) {
            accA += sWk[o] * Wq[o*128 + i];
            accV += sWo[o] * Wv[o*128 + i];
        }
        s_pA[p][i] = accA; s_pV[p][i] = accV;
        __syncthreads();
        if (tid < 128) {
            float v = s_pA[0][tid] + s_pA[1][tid] + s_pA[2][tid] + s_pA[3][tid];
            Afrag[fidxA(blk, tid)] = f2b(v);
        } else if (tid < 256) {
            int ii = tid - 128;
            float v = s_pV[0][ii] + s_pV[1][ii] + s_pV[2][ii] + s_pV[3][ii];
            Wovfrag[fidxA(blk, ii)] = f2b(v);
            sWovRow[ii] = v;
        }
        __syncthreads();
        {   // Wow2[blk][h] = sum_c Wov[blk][c] * W2[h][c]   (h in [0,32))
            int h = tid >> 4, sub = tid & 15;
            float a = 0.f;
            #pragma unroll
            for (int jj = 0; jj < 8; ++jj)
                a += sWovRow[sub*8 + jj] * W2[h*128 + sub*8 + jj];
            s_p2[h][sub] = a;
        }
        __syncthreads();
        if (tid < 32) {
            float v = 0.f;
            #pragma unroll
            for (int s = 0; s < 16; ++s) v += s_p2[tid][s];
            // A-frag (K=32): [(mt*64 + q*16 + lmm)*8 + j], m=blk, k=tid
            Wow2frag[(((blk >> 4)*64 + (tid >> 3)*16 + (blk & 15)))*8 + (tid & 7)] = f2b(v);
        }
    } else if (blk == 128) {
        __shared__ float s_r[2][4][128];
        float a1 = 0.f, a3 = 0.f;
        #pragma unroll 8
        for (int o = p*32; o < p*32 + 32; ++o) {
            a1 += Wk[o*128 + i] * bq[o];
            a3 += Wo[i*128 + o] * bv[o];
        }
        s_r[0][p][i] = a1; s_r[1][p][i] = a3;
        __syncthreads();
        if (tid < 128) {
            bA[tid] = s_r[0][0][tid] + s_r[0][1][tid] + s_r[0][2][tid] + s_r[0][3][tid];
        } else if (tid < 256) {
            int ii = tid - 128;
            bov[ii] = s_r[1][0][ii] + s_r[1][1][ii] + s_r[1][2][ii] + s_r[1][3][ii] + bo[ii];
        }
    } else {
        // blk == 129: fragment packs for W1 / W2
        for (int e = tid; e < 4096; e += 512) {
            int ii = e & 127, r2 = e >> 7;         // r2 in [0,32)
            {   // W1frag: B-operand of H=E*W1, elem B[k=ii][n=r2]
                int nt = r2 >> 4, lmm = r2 & 15;
                int ks = ii >> 5, q = (ii >> 3) & 3, j = ii & 7;
                W1frag[((nt*4 + ks)*64 + q*16 + lmm)*8 + j] = f2b(W1[ii*32 + r2]);
            }
            {   // W2frag: A-operand of G=W2*QK, elem A[m=r2][c=ii]
                int mt = r2 >> 4, lmm = r2 & 15;
                int ks = ii >> 5, q = (ii >> 3) & 3, j = ii & 7;
                W2frag[((mt*4 + ks)*64 + q*16 + lmm)*8 + j] = f2b(W2[r2*128 + ii]);
            }
        }
    }
}

// ---------------------------------------------------------------------------
// Kernel 2: fused main. Grid 1024 x 256; 16 n per block; ~40 KB LDS; 4 barriers.
// All 16 MFMA columns distinct (no lmm duplication) in QK/G/score/OUT.
__global__ void __launch_bounds__(256, 2)
k_main(const u16* __restrict__ xT, const float* __restrict__ coords,
       const int* __restrict__ idx, const float* __restrict__ Bg,
       const float* __restrict__ b1g, const float* __restrict__ b2g,
       const u16* __restrict__ Afrag, const u16* __restrict__ Wovfrag,
       const u16* __restrict__ W1frag, const u16* __restrict__ W2frag,
       const u16* __restrict__ Wow2frag,
       const float* __restrict__ bAg, const float* __restrict__ bovg,
       float* __restrict__ out)
{
    __shared__ __align__(16) u16   sH[256][40];      // H bf16 rows (n,k) x m
    __shared__ __align__(16) u16   s_qkb[16][136];   // qk bf16 [n][c]
    __shared__ __align__(16) u16   s_gb[16][40];     // g bf16 [n][m]
    __shared__ __align__(16) u16   s_xbb[16][136];   // xbar+b2 bf16 [n][c]
    __shared__ __align__(16) float s_del[256][4];
    __shared__ float s_attn[16][17];
    __shared__ u16   sHbar[32][18];                  // hbar bf16 [m][n]
    __shared__ __align__(16) float s_b2[128];
    __shared__ float s_bov[128], s_b1[32];
    __shared__ __align__(16) float sBgT[64][4];
    __shared__ int s_idx[256];

    const int tid = threadIdx.x;
    const int w = tid >> 6, l = tid & 63, lm = l & 15, lq = l >> 4;
    const int g0 = blockIdx.x * 16;
    const int bsel = g0 >> 13;
    const int n0 = g0 & 8191;
    const size_t bbase = ((size_t)bsel) << 13;
    const float inv_sqrtC = 0.08838834764831845f;

    // ---- preamble: biases/Bg + idx/delta + QK MFMA + qk pack (no barrier) ----
    if (tid < 128) { s_bov[tid] = bovg[tid]; s_b2[tid] = b2g[tid]; }
    else if (tid < 160) { s_b1[tid-128] = b1g[tid-128]; }
    sBgT[tid >> 2][tid & 3] = Bg[(tid & 3)*64 + (tid >> 2)];

    {   // idx + delta for all 256 (n,k) pairs: n = tid>>4, k = tid&15
        int j = idx[(size_t)g0*16 + tid];
        s_idx[tid] = j;
        float4 cj = *(const float4*)&coords[(size_t)(bbase + j)*4];
        float4 cn = *(const float4*)&coords[(size_t)(g0 + (tid >> 4))*4];
        *(float4*)s_del[tid] = make_float4(cj.x-cn.x, cj.y-cn.y, cj.z-cn.z, cj.w-cn.w);
    }
    {   // QK = A*X: B cols = 16 distinct points (lm); every lane stores.
        f32x4 accq[2] = {{0.f,0.f,0.f,0.f},{0.f,0.f,0.f,0.f}};
        const bf16x8* Af = (const bf16x8*)Afrag;
        bf16x8 bfr[4];
        #pragma unroll
        for (int ks = 0; ks < 4; ++ks)
            bfr[ks] = *(const bf16x8*)&xT[(((size_t)(g0 + lm)) << 7) + ks*32 + lq*8];
        #pragma unroll
        for (int mi = 0; mi < 2; ++mi) {
            const int ct = w*2 + mi;
            #pragma unroll
            for (int ks = 0; ks < 4; ++ks) {
                bf16x8 a = Af[(ct*4 + ks)*64 + l];
                accq[mi] = __builtin_amdgcn_mfma_f32_16x16x32_bf16(a, bfr[ks], accq[mi], 0, 0, 0);
            }
        }
        #pragma unroll
        for (int mi = 0; mi < 2; ++mi) {
            int c0 = (w*2 + mi)*16 + lq*4;
            float4 ba4 = *(const float4*)&bAg[c0];
            *(u64*)&s_qkb[lm][c0] = pack4(accq[mi][0] + ba4.x, accq[mi][1] + ba4.y,
                                          accq[mi][2] + ba4.z, accq[mi][3] + ba4.w);
        }
    }
    __syncthreads();   // B1

    // ---- H = relu(E*W1+b1) [all waves, 4 points each] ; G = W2*QK [w0-1] ----
    {
        const bf16x8* W1f = (const bf16x8*)W1frag;
        bf16x8 w1f[2][4];
        #pragma unroll
        for (int nt = 0; nt < 2; ++nt)
            #pragma unroll
            for (int ks = 0; ks < 4; ++ks) w1f[nt][ks] = W1f[(nt*4 + ks)*64 + l];
        #pragma unroll
        for (int mi = 0; mi < 4; ++mi) {
            const int mt = w*4 + mi;               // mt = point in [0,16), lm = k
            float4 d = *(const float4*)s_del[mt*16 + lm];
            bf16x8 ea[4];
            #pragma unroll
            for (int ksp = 0; ksp < 2; ++ksp) {
                #pragma unroll
                for (int jp = 0; jp < 4; ++jp) {
                    int f = ksp*32 + lq*8 + jp*2;
                    float4 ga = *(const float4*)sBgT[f];
                    float4 gb = *(const float4*)sBgT[f+1];
                    float p0 = d.x*ga.x + d.y*ga.y + d.z*ga.z + d.w*ga.w;
                    float p1 = d.x*gb.x + d.y*gb.y + d.z*gb.z + d.w*gb.w;
                    p0 -= floorf(p0); p1 -= floorf(p1);
                    ((u32*)&ea[ksp])[jp]   = (u32)f2b(__builtin_amdgcn_sinf(p0))
                                           | ((u32)f2b(__builtin_amdgcn_sinf(p1)) << 16);
                    ((u32*)&ea[ksp+2])[jp] = (u32)f2b(__builtin_amdgcn_cosf(p0))
                                           | ((u32)f2b(__builtin_amdgcn_cosf(p1)) << 16);
                }
            }
            f32x4 acch[2] = {{0.f,0.f,0.f,0.f},{0.f,0.f,0.f,0.f}};
            #pragma unroll
            for (int ks = 0; ks < 4; ++ks) {
                acch[0] = __builtin_amdgcn_mfma_f32_16x16x32_bf16(ea[ks], w1f[0][ks], acch[0], 0,0,0);
                acch[1] = __builtin_amdgcn_mfma_f32_16x16x32_bf16(ea[ks], w1f[1][ks], acch[1], 0,0,0);
            }
            #pragma unroll
            for (int nt = 0; nt < 2; ++nt) {
                float b1v = s_b1[nt*16 + lm];
                #pragma unroll
                for (int r = 0; r < 4; ++r)
                    sH[mt*16 + lq*4 + r][nt*16 + lm] = f2b(fmaxf(acch[nt][r] + b1v, 0.f));
            }
        }
    }
    if (w < 2) {
        // G = W2*QK (m-tile = w); B cols = 16 distinct points
        const bf16x8* W2f = (const bf16x8*)W2frag;
        f32x4 accg = {0.f,0.f,0.f,0.f};
        #pragma unroll
        for (int ks = 0; ks < 4; ++ks) {
            bf16x8 a = W2f[(w*4 + ks)*64 + l];
            bf16x8 bv = *(const bf16x8*)&s_qkb[lm][ks*32 + lq*8];
            accg = __builtin_amdgcn_mfma_f32_16x16x32_bf16(a, bv, accg, 0, 0, 0);
        }
        {
            int m0 = w*16 + lq*4;
            *(u64*)&s_gb[lm][m0] = pack4(accg[0], accg[1], accg[2], accg[3]);
        }
    }
    __syncthreads();   // B2

    // ---- scores: S = [Xnb | H] · [qk ; g] + in-wave softmax (4 points/wave) ----
    {
        bf16x8 bq4[5];
        #pragma unroll
        for (int ks = 0; ks < 4; ++ks) bq4[ks] = *(const bf16x8*)&s_qkb[lm][ks*32 + lq*8];
        bq4[4] = *(const bf16x8*)&s_gb[lm][lq*8];
        #pragma unroll
        for (int mi = 0; mi < 4; ++mi) {
            const int mt = w*4 + mi;               // mt = point, lm = k (A rows)
            bf16x8 xnb[4];
            const size_t rb = ((size_t)(bbase + s_idx[mt*16 + lm])) << 7;
            #pragma unroll
            for (int ks = 0; ks < 4; ++ks)
                xnb[ks] = *(const bf16x8*)&xT[rb + ks*32 + lq*8];
            f32x4 acc = {0.f,0.f,0.f,0.f};
            #pragma unroll
            for (int ks = 0; ks < 4; ++ks)
                acc = __builtin_amdgcn_mfma_f32_16x16x32_bf16(xnb[ks], bq4[ks], acc, 0, 0, 0);
            {
                bf16x8 a = *(const bf16x8*)&sH[mt*16 + lm][lq*8];
                acc = __builtin_amdgcn_mfma_f32_16x16x32_bf16(a, bq4[4], acc, 0, 0, 0);
            }
            // in-wave softmax over K=16: k = lq*4+r; reduce across lq via
            // xor 16/32; e0 term dropped (k-independent => shift-invariant).
            float s0 = acc[0]*inv_sqrtC, s1 = acc[1]*inv_sqrtC;
            float s2 = acc[2]*inv_sqrtC, s3 = acc[3]*inv_sqrtC;
            float mx = fmaxf(fmaxf(s0, s1), fmaxf(s2, s3));
            mx = fmaxf(mx, __shfl_xor(mx, 16));
            mx = fmaxf(mx, __shfl_xor(mx, 32));
            float e0 = __expf(s0 - mx), e1 = __expf(s1 - mx);
            float e2 = __expf(s2 - mx), e3 = __expf(s3 - mx);
            float sm = (e0 + e1) + (e2 + e3);
            sm += __shfl_xor(sm, 16);
            sm += __shfl_xor(sm, 32);
            if (lm == mt) {
                float inv = 1.0f / sm;
                s_attn[mt][lq*4 + 0] = e0*inv;
                s_attn[mt][lq*4 + 1] = e1*inv;
                s_attn[mt][lq*4 + 2] = e2*inv;
                s_attn[mt][lq*4 + 3] = e3*inv;
            }
        }
    }
    __syncthreads();   // B3

    // ---- xbar (+b2) -> s_xbb (uint4 gathers) ; hbar -> sHbar (all threads) ----
    {
        int n = tid >> 4, cs = tid & 15, c0 = cs*8;
        float a0[16];
        #pragma unroll
        for (int k = 0; k < 16; ++k) a0[k] = s_attn[n][k];
        float4 f0 = *(const float4*)&s_b2[c0];
        float4 f1 = *(const float4*)&s_b2[c0+4];
        #pragma unroll
        for (int k = 0; k < 16; ++k) {
            uint4 v = *(const uint4*)&xT[(((size_t)(bbase + s_idx[n*16 + k])) << 7) + c0];
            f0.x += a0[k]*bl(v.x); f0.y += a0[k]*bh(v.x);
            f0.z += a0[k]*bl(v.y); f0.w += a0[k]*bh(v.y);
            f1.x += a0[k]*bl(v.z); f1.y += a0[k]*bh(v.z);
            f1.z += a0[k]*bl(v.w); f1.w += a0[k]*bh(v.w);
        }
        *(u64*)&s_xbb[n][c0]   = pack4(f0.x, f0.y, f0.z, f0.w);
        *(u64*)&s_xbb[n][c0+4] = pack4(f1.x, f1.y, f1.z, f1.w);
        // hbar: 16n x 32m = 512 -> each thread does 2 hidden units
        int m0 = cs*2;
        float h0 = 0.f, h1 = 0.f;
        #pragma unroll
        for (int k = 0; k < 16; ++k) {
            float ak = a0[k];
            u32 hv = *(const u32*)&sH[n*16 + k][m0];
            h0 += ak * bl(hv);
            h1 += ak * bh(hv);
        }
        sHbar[m0][n]   = f2b(h0);
        sHbar[m0+1][n] = f2b(h1);
    }
    __syncthreads();   // B4

    // ---- OUT = Wov*xbar + Wow2*Hbar + bov -> global (16 distinct cols) ----
    {
        const bf16x8* Wvf = (const bf16x8*)Wovfrag;
        const bf16x8* W2f = (const bf16x8*)Wow2frag;
        bf16x8 bv[4];
        #pragma unroll
        for (int ks = 0; ks < 4; ++ks) bv[ks] = *(const bf16x8*)&s_xbb[lm][ks*32 + lq*8];
        bf16x8 bvh;
        #pragma unroll
        for (int j = 0; j < 8; ++j) bvh[j] = (short)sHbar[lq*8 + j][lm];
        #pragma unroll
        for (int mi = 0; mi < 2; ++mi) {
            const int ct = w*2 + mi;
            f32x4 acco = {0.f,0.f,0.f,0.f};
            acco = __builtin_amdgcn_mfma_f32_16x16x32_bf16(W2f[ct*64 + l], bvh, acco, 0, 0, 0);
            #pragma unroll
            for (int ks = 0; ks < 4; ++ks) {
                bf16x8 a = Wvf[(ct*4 + ks)*64 + l];
                acco = __builtin_amdgcn_mfma_f32_16x16x32_bf16(a, bv[ks], acco, 0, 0, 0);
            }
            #pragma unroll
            for (int r = 0; r < 4; ++r) {
                int o = ct*16 + lq*4 + r;
                out[(((size_t)(bsel*128 + o)) << 13) + n0 + lm] = acco[r] + s_bov[o];
            }
        }
    }
}

// ---------------------------------------------------------------------------
extern "C" void kernel_launch(void* const* d_in, const int* in_sizes, int n_in,
                              void* d_out, int out_size, void* d_ws, size_t ws_size,
                              hipStream_t stream)
{
    const float* x      = (const float*)d_in[0];
    const float* coords = (const float*)d_in[1];
    const int*   idx    = (const int*)d_in[2];
    const float* Bg     = (const float*)d_in[3];
    const float* W1     = (const float*)d_in[4];
    const float* b1     = (const float*)d_in[5];
    const float* W2     = (const float*)d_in[6];
    const float* b2     = (const float*)d_in[7];
    const float* Wq     = (const float*)d_in[8];
    const float* bq     = (const float*)d_in[9];
    const float* Wk     = (const float*)d_in[10];
    const float* bk     = (const float*)d_in[11];
    const float* Wv     = (const float*)d_in[12];
    const float* bv     = (const float*)d_in[13];
    const float* Wo     = (const float*)d_in[14];
    const float* bo     = (const float*)d_in[15];
    float* out = (float*)d_out;
    (void)bk;

    char* ws = (char*)d_ws;
    u16*   Afrag    = (u16*)(ws);              // 32768 B
    u16*   Wovfrag  = (u16*)(ws + 32768);      // 32768 B
    u16*   W1frag   = (u16*)(ws + 65536);      // 8192 B
    u16*   W2frag   = (u16*)(ws + 73728);      // 8192 B
    u16*   Wow2frag = (u16*)(ws + 81920);      // 8192 B
    float* bA       = (float*)(ws + 90112);    // 512 B
    float* bov      = (float*)(ws + 90624);    // 512 B
    u16*   xT       = (u16*)(ws + 94208);      // 4 MiB

    k_pt<<<2178, 512, 0, stream>>>(x, Wq, bq, Wk, Wv, bv, Wo, bo, W1, W2,
                                   Afrag, Wovfrag, W1frag, W2frag, Wow2frag,
                                   bA, bov, xT);
    k_main<<<1024, 256, 0, stream>>>(xT, coords, idx, Bg, b1, b2,
                                     Afrag, Wovfrag, W1frag, W2frag, Wow2frag,
                                     bA, bov, out);
}

// Round 6
// 118.314 us; speedup vs baseline: 1.1072x; 1.0451x over previous
//
#include <hip/hip_runtime.h>

// LSGA fused kernel, round 12: transcendental-free H stage via sincos table.
// Round-11 post-mortem: k_main ~30us; H stage dominated by 128 quarter-rate
// sin/cos per thread in a serial dot->fract->sin chain. Identity:
//   sin 2pi(pj-pn) = sj*cn - cj*sn ;  cos 2pi(pj-pn) = cj*cn + sj*sn
// with per-point phases precomputed ONCE into scT[16384][64] (bf16 s|c in
// u32, 4MB, L2/L3-resident) by 256 new k_pt blocks. H stage: no sin/cos,
// no floor, no Bg dots, no coords gather; s_del/sBgT deleted, s_scn (4KB)
// stages the block's own 16 points.
// Keeps: NPB=16, e0 deleted, in-wave softmax, Wow2 fold, 4 barriers, (256,2),
// scalar f2b only (no inline asm).
//
// MFMA 16x16x32 lane mappings (verified rounds 3/4/5):
//   A-frag:  A[m = lane&15][k = (lane>>4)*8 + j]
//   B-frag:  B[k = (lane>>4)*8 + j][n = lane&15]
//   C/D:     col = lane&15, row = (lane>>4)*4 + reg

using u16 = unsigned short;
using u32 = unsigned int;
using u64 = unsigned long long;

typedef short bf16x8 __attribute__((ext_vector_type(8)));
typedef float f32x4  __attribute__((ext_vector_type(4)));

__device__ __forceinline__ float bl(u32 u) { return __uint_as_float(u << 16); }
__device__ __forceinline__ float bh(u32 u) { return __uint_as_float(u & 0xffff0000u); }
__device__ __forceinline__ u16 f2b(float f) {
    u32 u = __float_as_uint(f);
    u32 r = u + 0x7fffu + ((u >> 16) & 1u);   // RNE
    return (u16)(r >> 16);
}
__device__ __forceinline__ u32 pk2(float lo, float hi) {
    return (u32)f2b(lo) | ((u32)f2b(hi) << 16);
}
__device__ __forceinline__ u64 pack4(float a, float b, float c, float d) {
    return (u64)pk2(a, b) | ((u64)pk2(c, d) << 32);
}
// A-operand frag flat index for element [m][c] of a 128-col operand
__device__ __forceinline__ int fidxA(int m, int c) {
    return (((m >> 4)*4 + (c >> 5))*64 + ((c >> 3) & 3)*16 + (m & 15))*8 + (c & 7);
}

// ---------------------------------------------------------------------------
// Kernel 1: blocks 0..129 weight fuse/pack, 130..2177 transpose,
//           2178..2433 per-point sincos table.
__global__ void __launch_bounds__(512)
k_pt(const float* __restrict__ x, const float* __restrict__ coords,
     const float* __restrict__ Bg,
     const float* __restrict__ Wq, const float* __restrict__ bq,
     const float* __restrict__ Wk,
     const float* __restrict__ Wv, const float* __restrict__ bv,
     const float* __restrict__ Wo, const float* __restrict__ bo,
     const float* __restrict__ W1, const float* __restrict__ W2,
     u16* __restrict__ Afrag, u16* __restrict__ Wovfrag,
     u16* __restrict__ W1frag, u16* __restrict__ W2frag,
     u16* __restrict__ Wow2frag,
     float* __restrict__ bA, float* __restrict__ bov,
     u16* __restrict__ xT, u32* __restrict__ scT)
{
    const int blk = blockIdx.x, tid = threadIdx.x;

    if (blk >= 2178) {
        // ---- per-point sincos table: scT[p][f] = bf16 sin | bf16 cos << 16 ----
        __shared__ float sBg[64][4];
        if (tid < 256) sBg[tid >> 2][tid & 3] = Bg[(tid & 3)*64 + (tid >> 2)];
        __syncthreads();
        const int p  = (blk - 2178)*64 + (tid >> 3);    // point in [0,16384)
        const int f0 = (tid & 7)*8;                     // 8 freqs per thread
        float4 c = *(const float4*)&coords[(size_t)p*4];
        u32 ov[8];
        #pragma unroll
        for (int j = 0; j < 8; ++j) {
            float4 g = *(const float4*)sBg[f0 + j];
            float ph = c.x*g.x + c.y*g.y + c.z*g.z + c.w*g.w;
            ph -= floorf(ph);
            ov[j] = pk2(__builtin_amdgcn_sinf(ph), __builtin_amdgcn_cosf(ph));
        }
        u32* dst = &scT[(size_t)p*64 + f0];
        *(uint4*)dst       = make_uint4(ov[0], ov[1], ov[2], ov[3]);
        *(uint4*)(dst + 4) = make_uint4(ov[4], ov[5], ov[6], ov[7]);
        return;
    }

    if (blk >= 130) {
        // ---- transpose x[b][c][n] -> xT[b][n][c] (bf16), 32x32 tiles ----
        __shared__ u16 tile[32][33];
        const int blk2 = blk - 130;
        const int b  = blk2 >> 10;
        const int ct = (blk2 >> 8) & 3;
        const int nt = blk2 & 255;
        const int tx = tid & 31, ty = tid >> 5;      // 32 x 16
        const size_t xb = (size_t)b * 128 * 8192;
        #pragma unroll
        for (int j = 0; j < 2; ++j) {
            int c = ct*32 + ty + j*16;
            tile[ty + j*16][tx] = f2b(x[xb + (size_t)c * 8192 + (size_t)(nt*32 + tx)]);
        }
        __syncthreads();
        #pragma unroll
        for (int j = 0; j < 2; ++j) {
            int n = nt*32 + ty + j*16;
            xT[xb + (size_t)n * 128 + (size_t)(ct*32 + tx)] = tile[tx][ty + j*16];
        }
        return;
    }

    const int i = tid & 127, p = tid >> 7;          // 4-way K-split
    if (blk < 128) {
        __shared__ float sWk[128], sWo[128];
        __shared__ float s_pA[4][128], s_pV[4][128];
        __shared__ float sWovRow[128];
        __shared__ float s_p2[32][17];
        if (tid < 128) sWk[tid] = Wk[tid*128 + blk];
        else if (tid < 256) sWo[tid-128] = Wo[blk*128 + (tid-128)];
        __syncthreads();
        float accA = 0.f, accV = 0.f;
        #pragma unroll 8
        for (int o = p*32; o < p*32 + 32; ++o) {
            accA += sWk[o] * Wq[o*128 + i];
            accV += sWo[o] * Wv[o*128 + i];
        }
        s_pA[p][i] = accA; s_pV[p][i] = accV;
        __syncthreads();
        if (tid < 128) {
            float v = s_pA[0][tid] + s_pA[1][tid] + s_pA[2][tid] + s_pA[3][tid];
            Afrag[fidxA(blk, tid)] = f2b(v);
        } else if (tid < 256) {
            int ii = tid - 128;
            float v = s_pV[0][ii] + s_pV[1][ii] + s_pV[2][ii] + s_pV[3][ii];
            Wovfrag[fidxA(blk, ii)] = f2b(v);
            sWovRow[ii] = v;
        }
        __syncthreads();
        {   // Wow2[blk][h] = sum_c Wov[blk][c] * W2[h][c]   (h in [0,32))
            int h = tid >> 4, sub = tid & 15;
            float a = 0.f;
            #pragma unroll
            for (int jj = 0; jj < 8; ++jj)
                a += sWovRow[sub*8 + jj] * W2[h*128 + sub*8 + jj];
            s_p2[h][sub] = a;
        }
        __syncthreads();
        if (tid < 32) {
            float v = 0.f;
            #pragma unroll
            for (int s = 0; s < 16; ++s) v += s_p2[tid][s];
            // A-frag (K=32): [(mt*64 + q*16 + lmm)*8 + j], m=blk, k=tid
            Wow2frag[(((blk >> 4)*64 + (tid >> 3)*16 + (blk & 15)))*8 + (tid & 7)] = f2b(v);
        }
    } else if (blk == 128) {
        __shared__ float s_r[2][4][128];
        float a1 = 0.f, a3 = 0.f;
        #pragma unroll 8
        for (int o = p*32; o < p*32 + 32; ++o) {
            a1 += Wk[o*128 + i] * bq[o];
            a3 += Wo[i*128 + o] * bv[o];
        }
        s_r[0][p][i] = a1; s_r[1][p][i] = a3;
        __syncthreads();
        if (tid < 128) {
            bA[tid] = s_r[0][0][tid] + s_r[0][1][tid] + s_r[0][2][tid] + s_r[0][3][tid];
        } else if (tid < 256) {
            int ii = tid - 128;
            bov[ii] = s_r[1][0][ii] + s_r[1][1][ii] + s_r[1][2][ii] + s_r[1][3][ii] + bo[ii];
        }
    } else {
        // blk == 129: fragment packs for W1 / W2
        for (int e = tid; e < 4096; e += 512) {
            int ii = e & 127, r2 = e >> 7;         // r2 in [0,32)
            {   // W1frag: B-operand of H=E*W1, elem B[k=ii][n=r2]
                int nt = r2 >> 4, lmm = r2 & 15;
                int ks = ii >> 5, q = (ii >> 3) & 3, j = ii & 7;
                W1frag[((nt*4 + ks)*64 + q*16 + lmm)*8 + j] = f2b(W1[ii*32 + r2]);
            }
            {   // W2frag: A-operand of G=W2*QK, elem A[m=r2][c=ii]
                int mt = r2 >> 4, lmm = r2 & 15;
                int ks = ii >> 5, q = (ii >> 3) & 3, j = ii & 7;
                W2frag[((mt*4 + ks)*64 + q*16 + lmm)*8 + j] = f2b(W2[r2*128 + ii]);
            }
        }
    }
}

// ---------------------------------------------------------------------------
// Kernel 2: fused main. Grid 1024 x 256; 16 n per block; ~40 KB LDS; 4 barriers.
__global__ void __launch_bounds__(256, 2)
k_main(const u16* __restrict__ xT, const u32* __restrict__ scT,
       const int* __restrict__ idx,
       const float* __restrict__ b1g, const float* __restrict__ b2g,
       const u16* __restrict__ Afrag, const u16* __restrict__ Wovfrag,
       const u16* __restrict__ W1frag, const u16* __restrict__ W2frag,
       const u16* __restrict__ Wow2frag,
       const float* __restrict__ bAg, const float* __restrict__ bovg,
       float* __restrict__ out)
{
    __shared__ __align__(16) u16   sH[256][40];      // H bf16 rows (n,k) x m
    __shared__ __align__(16) u16   s_qkb[16][136];   // qk bf16 [n][c]
    __shared__ __align__(16) u16   s_gb[16][40];     // g bf16 [n][m]
    __shared__ __align__(16) u16   s_xbb[16][136];   // xbar+b2 bf16 [n][c]
    __shared__ __align__(16) u32   s_scn[16][64];    // own-point sincos
    __shared__ float s_attn[16][17];
    __shared__ u16   sHbar[32][18];                  // hbar bf16 [m][n]
    __shared__ __align__(16) float s_b2[128];
    __shared__ float s_bov[128], s_b1[32];
    __shared__ int s_idx[256];

    const int tid = threadIdx.x;
    const int w = tid >> 6, l = tid & 63, lm = l & 15, lq = l >> 4;
    const int g0 = blockIdx.x * 16;
    const int bsel = g0 >> 13;
    const int n0 = g0 & 8191;
    const size_t bbase = ((size_t)bsel) << 13;
    const float inv_sqrtC = 0.08838834764831845f;

    // ---- preamble: biases + own-sc stage + idx + QK MFMA + qk pack ----
    if (tid < 128) { s_bov[tid] = bovg[tid]; s_b2[tid] = b2g[tid]; }
    else if (tid < 160) { s_b1[tid-128] = b1g[tid-128]; }

    // own 16 points' sincos rows (contiguous in scT at g0)
    *(uint4*)&s_scn[tid >> 4][(tid & 15)*4] =
        *(const uint4*)&scT[(size_t)(g0 + (tid >> 4))*64 + (tid & 15)*4];

    s_idx[tid] = idx[(size_t)g0*16 + tid];

    {   // QK = A*X: B cols = 16 distinct points (lm); every lane stores.
        f32x4 accq[2] = {{0.f,0.f,0.f,0.f},{0.f,0.f,0.f,0.f}};
        const bf16x8* Af = (const bf16x8*)Afrag;
        bf16x8 bfr[4];
        #pragma unroll
        for (int ks = 0; ks < 4; ++ks)
            bfr[ks] = *(const bf16x8*)&xT[(((size_t)(g0 + lm)) << 7) + ks*32 + lq*8];
        #pragma unroll
        for (int mi = 0; mi < 2; ++mi) {
            const int ct = w*2 + mi;
            #pragma unroll
            for (int ks = 0; ks < 4; ++ks) {
                bf16x8 a = Af[(ct*4 + ks)*64 + l];
                accq[mi] = __builtin_amdgcn_mfma_f32_16x16x32_bf16(a, bfr[ks], accq[mi], 0, 0, 0);
            }
        }
        #pragma unroll
        for (int mi = 0; mi < 2; ++mi) {
            int c0 = (w*2 + mi)*16 + lq*4;
            float4 ba4 = *(const float4*)&bAg[c0];
            *(u64*)&s_qkb[lm][c0] = pack4(accq[mi][0] + ba4.x, accq[mi][1] + ba4.y,
                                          accq[mi][2] + ba4.z, accq[mi][3] + ba4.w);
        }
    }
    __syncthreads();   // B1

    // ---- H = relu(E*W1+b1): E via angle-difference identity (no trig) ----
    {
        const bf16x8* W1f = (const bf16x8*)W1frag;
        bf16x8 w1f[2][4];
        #pragma unroll
        for (int nt = 0; nt < 2; ++nt)
            #pragma unroll
            for (int ks = 0; ks < 4; ++ks) w1f[nt][ks] = W1f[(nt*4 + ks)*64 + l];
        #pragma unroll
        for (int mi = 0; mi < 4; ++mi) {
            const int mt = w*4 + mi;               // point in [0,16), lm = k
            const int j = s_idx[mt*16 + lm];
            const u32* scj = &scT[(size_t)(bbase + j)*64];
            union { uint4 q[4]; u32 u[16]; } J, N;
            J.q[0] = *(const uint4*)&scj[lq*8];
            J.q[1] = *(const uint4*)&scj[lq*8 + 4];
            J.q[2] = *(const uint4*)&scj[32 + lq*8];
            J.q[3] = *(const uint4*)&scj[32 + lq*8 + 4];
            N.q[0] = *(const uint4*)&s_scn[mt][lq*8];
            N.q[1] = *(const uint4*)&s_scn[mt][lq*8 + 4];
            N.q[2] = *(const uint4*)&s_scn[mt][32 + lq*8];
            N.q[3] = *(const uint4*)&s_scn[mt][32 + lq*8 + 4];
            bf16x8 ea[4];
            #pragma unroll
            for (int ksp = 0; ksp < 2; ++ksp) {
                #pragma unroll
                for (int jp = 0; jp < 4; ++jp) {
                    int t0 = ksp*8 + jp*2;
                    u32 j0 = J.u[t0], j1 = J.u[t0+1];
                    u32 n0u = N.u[t0], n1u = N.u[t0+1];
                    float sj0 = bl(j0), cj0 = bh(j0), sn0 = bl(n0u), cn0 = bh(n0u);
                    float sj1 = bl(j1), cj1 = bh(j1), sn1 = bl(n1u), cn1 = bh(n1u);
                    float sv0 = sj0*cn0 - cj0*sn0, cv0 = cj0*cn0 + sj0*sn0;
                    float sv1 = sj1*cn1 - cj1*sn1, cv1 = cj1*cn1 + sj1*sn1;
                    ((u32*)&ea[ksp])[jp]   = pk2(sv0, sv1);
                    ((u32*)&ea[ksp+2])[jp] = pk2(cv0, cv1);
                }
            }
            f32x4 acch[2] = {{0.f,0.f,0.f,0.f},{0.f,0.f,0.f,0.f}};
            #pragma unroll
            for (int ks = 0; ks < 4; ++ks) {
                acch[0] = __builtin_amdgcn_mfma_f32_16x16x32_bf16(ea[ks], w1f[0][ks], acch[0], 0,0,0);
                acch[1] = __builtin_amdgcn_mfma_f32_16x16x32_bf16(ea[ks], w1f[1][ks], acch[1], 0,0,0);
            }
            #pragma unroll
            for (int nt = 0; nt < 2; ++nt) {
                float b1v = s_b1[nt*16 + lm];
                #pragma unroll
                for (int r = 0; r < 4; ++r)
                    sH[mt*16 + lq*4 + r][nt*16 + lm] = f2b(fmaxf(acch[nt][r] + b1v, 0.f));
            }
        }
    }
    if (w < 2) {
        // G = W2*QK (m-tile = w); B cols = 16 distinct points
        const bf16x8* W2f = (const bf16x8*)W2frag;
        f32x4 accg = {0.f,0.f,0.f,0.f};
        #pragma unroll
        for (int ks = 0; ks < 4; ++ks) {
            bf16x8 a = W2f[(w*4 + ks)*64 + l];
            bf16x8 bv = *(const bf16x8*)&s_qkb[lm][ks*32 + lq*8];
            accg = __builtin_amdgcn_mfma_f32_16x16x32_bf16(a, bv, accg, 0, 0, 0);
        }
        {
            int m0 = w*16 + lq*4;
            *(u64*)&s_gb[lm][m0] = pack4(accg[0], accg[1], accg[2], accg[3]);
        }
    }
    __syncthreads();   // B2

    // ---- scores: S = [Xnb | H] · [qk ; g] + in-wave softmax (4 points/wave) ----
    {
        bf16x8 bq4[5];
        #pragma unroll
        for (int ks = 0; ks < 4; ++ks) bq4[ks] = *(const bf16x8*)&s_qkb[lm][ks*32 + lq*8];
        bq4[4] = *(const bf16x8*)&s_gb[lm][lq*8];
        #pragma unroll
        for (int mi = 0; mi < 4; ++mi) {
            const int mt = w*4 + mi;               // mt = point, lm = k (A rows)
            bf16x8 xnb[4];
            const size_t rb = ((size_t)(bbase + s_idx[mt*16 + lm])) << 7;
            #pragma unroll
            for (int ks = 0; ks < 4; ++ks)
                xnb[ks] = *(const bf16x8*)&xT[rb + ks*32 + lq*8];
            f32x4 acc = {0.f,0.f,0.f,0.f};
            #pragma unroll
            for (int ks = 0; ks < 4; ++ks)
                acc = __builtin_amdgcn_mfma_f32_16x16x32_bf16(xnb[ks], bq4[ks], acc, 0, 0, 0);
            {
                bf16x8 a = *(const bf16x8*)&sH[mt*16 + lm][lq*8];
                acc = __builtin_amdgcn_mfma_f32_16x16x32_bf16(a, bq4[4], acc, 0, 0, 0);
            }
            // in-wave softmax over K=16: k = lq*4+r; reduce across lq via
            // xor 16/32; e0 term dropped (k-independent => shift-invariant).
            float s0 = acc[0]*inv_sqrtC, s1 = acc[1]*inv_sqrtC;
            float s2 = acc[2]*inv_sqrtC, s3 = acc[3]*inv_sqrtC;
            float mx = fmaxf(fmaxf(s0, s1), fmaxf(s2, s3));
            mx = fmaxf(mx, __shfl_xor(mx, 16));
            mx = fmaxf(mx, __shfl_xor(mx, 32));
            float e0 = __expf(s0 - mx), e1 = __expf(s1 - mx);
            float e2 = __expf(s2 - mx), e3 = __expf(s3 - mx);
            float sm = (e0 + e1) + (e2 + e3);
            sm += __shfl_xor(sm, 16);
            sm += __shfl_xor(sm, 32);
            if (lm == mt) {
                float inv = 1.0f / sm;
                s_attn[mt][lq*4 + 0] = e0*inv;
                s_attn[mt][lq*4 + 1] = e1*inv;
                s_attn[mt][lq*4 + 2] = e2*inv;
                s_attn[mt][lq*4 + 3] = e3*inv;
            }
        }
    }
    __syncthreads();   // B3

    // ---- xbar (+b2) -> s_xbb (uint4 gathers) ; hbar -> sHbar (all threads) ----
    {
        int n = tid >> 4, cs = tid & 15, c0 = cs*8;
        float a0[16];
        #pragma unroll
        for (int k = 0; k < 16; ++k) a0[k] = s_attn[n][k];
        float4 f0 = *(const float4*)&s_b2[c0];
        float4 f1 = *(const float4*)&s_b2[c0+4];
        #pragma unroll
        for (int k = 0; k < 16; ++k) {
            uint4 v = *(const uint4*)&xT[(((size_t)(bbase + s_idx[n*16 + k])) << 7) + c0];
            f0.x += a0[k]*bl(v.x); f0.y += a0[k]*bh(v.x);
            f0.z += a0[k]*bl(v.y); f0.w += a0[k]*bh(v.y);
            f1.x += a0[k]*bl(v.z); f1.y += a0[k]*bh(v.z);
            f1.z += a0[k]*bl(v.w); f1.w += a0[k]*bh(v.w);
        }
        *(u64*)&s_xbb[n][c0]   = pack4(f0.x, f0.y, f0.z, f0.w);
        *(u64*)&s_xbb[n][c0+4] = pack4(f1.x, f1.y, f1.z, f1.w);
        // hbar: 16n x 32m = 512 -> each thread does 2 hidden units
        int m0 = cs*2;
        float h0 = 0.f, h1 = 0.f;
        #pragma unroll
        for (int k = 0; k < 16; ++k) {
            float ak = a0[k];
            u32 hv = *(const u32*)&sH[n*16 + k][m0];
            h0 += ak * bl(hv);
            h1 += ak * bh(hv);
        }
        sHbar[m0][n]   = f2b(h0);
        sHbar[m0+1][n] = f2b(h1);
    }
    __syncthreads();   // B4

    // ---- OUT = Wov*xbar + Wow2*Hbar + bov -> global (16 distinct cols) ----
    {
        const bf16x8* Wvf = (const bf16x8*)Wovfrag;
        const bf16x8* W2f = (const bf16x8*)Wow2frag;
        bf16x8 bv[4];
        #pragma unroll
        for (int ks = 0; ks < 4; ++ks) bv[ks] = *(const bf16x8*)&s_xbb[lm][ks*32 + lq*8];
        bf16x8 bvh;
        #pragma unroll
        for (int j = 0; j < 8; ++j) bvh[j] = (short)sHbar[lq*8 + j][lm];
        #pragma unroll
        for (int mi = 0; mi < 2; ++mi) {
            const int ct = w*2 + mi;
            f32x4 acco = {0.f,0.f,0.f,0.f};
            acco = __builtin_amdgcn_mfma_f32_16x16x32_bf16(W2f[ct*64 + l], bvh, acco, 0, 0, 0);
            #pragma unroll
            for (int ks = 0; ks < 4; ++ks) {
                bf16x8 a = Wvf[(ct*4 + ks)*64 + l];
                acco = __builtin_amdgcn_mfma_f32_16x16x32_bf16(a, bv[ks], acco, 0, 0, 0);
            }
            #pragma unroll
            for (int r = 0; r < 4; ++r) {
                int o = ct*16 + lq*4 + r;
                out[(((size_t)(bsel*128 + o)) << 13) + n0 + lm] = acco[r] + s_bov[o];
            }
        }
    }
}

// ---------------------------------------------------------------------------
extern "C" void kernel_launch(void* const* d_in, const int* in_sizes, int n_in,
                              void* d_out, int out_size, void* d_ws, size_t ws_size,
                              hipStream_t stream)
{
    const float* x      = (const float*)d_in[0];
    const float* coords = (const float*)d_in[1];
    const int*   idx    = (const int*)d_in[2];
    const float* Bg     = (const float*)d_in[3];
    const float* W1     = (const float*)d_in[4];
    const float* b1     = (const float*)d_in[5];
    const float* W2     = (const float*)d_in[6];
    const float* b2     = (const float*)d_in[7];
    const float* Wq     = (const float*)d_in[8];
    const float* bq     = (const float*)d_in[9];
    const float* Wk     = (const float*)d_in[10];
    const float* bk     = (const float*)d_in[11];
    const float* Wv     = (const float*)d_in[12];
    const float* bv     = (const float*)d_in[13];
    const float* Wo     = (const float*)d_in[14];
    const float* bo     = (const float*)d_in[15];
    float* out = (float*)d_out;
    (void)bk;

    char* ws = (char*)d_ws;
    u16*   Afrag    = (u16*)(ws);              // 32768 B
    u16*   Wovfrag  = (u16*)(ws + 32768);      // 32768 B
    u16*   W1frag   = (u16*)(ws + 65536);      // 8192 B
    u16*   W2frag   = (u16*)(ws + 73728);      // 8192 B
    u16*   Wow2frag = (u16*)(ws + 81920);      // 8192 B
    float* bA       = (float*)(ws + 90112);    // 512 B
    float* bov      = (float*)(ws + 90624);    // 512 B
    u16*   xT       = (u16*)(ws + 94208);      // 4 MiB
    u32*   scT      = (u32*)(ws + 94208 + 4194304);   // 4 MiB

    k_pt<<<2434, 512, 0, stream>>>(x, coords, Bg, Wq, bq, Wk, Wv, bv, Wo, bo,
                                   W1, W2,
                                   Afrag, Wovfrag, W1frag, W2frag, Wow2frag,
                                   bA, bov, xT, scT);
    k_main<<<1024, 256, 0, stream>>>(xT, scT, idx, b1, b2,
                                     Afrag, Wovfrag, W1frag, W2frag, Wow2frag,
                                     bA, bov, out);
}